// Round 1
// baseline (472.585 us; speedup 1.0000x reference)
//
#include <hip/hip_runtime.h>

// MoE transformer block: LN1 -> QKV -> RoPE -> causal flash attn -> proj+res
// -> LN2 -> noisy top-2 router (cap 512) -> expert FFN -> combine.
// All big GEMMs: bf16 MFMA 16x16x32, fp32 weights converted in LDS staging.

#define TB 1024   // T
#define DD 1024   // D
#define NTOK 2048 // B*T
#define NEXPERT 8
#define CAPN 512
#define DFF 4096

typedef __attribute__((ext_vector_type(4))) float f32x4;
typedef __attribute__((ext_vector_type(8))) short short8;
typedef __attribute__((ext_vector_type(4))) short short4v;
typedef unsigned short u16;

__device__ __forceinline__ u16 f2bf(float f){
  union { float f; unsigned int u; } v; v.f = f;
  unsigned int u = v.u;
  unsigned int r = (u + 0x7fffu + ((u >> 16) & 1u)) >> 16;
  return (u16)r;
}
__device__ __forceinline__ float bf2f(u16 b){
  union { unsigned int u; float f; } v; v.u = ((unsigned int)b) << 16;
  return v.f;
}
__device__ __forceinline__ float waveRedSum(float v){
#pragma unroll
  for (int o = 1; o < 64; o <<= 1) v += __shfl_xor(v, o);
  return v;
}

// ---------------------------------------------------------------- GEMM core
// C(128x128) tile, 4 waves (2x2), A bf16 [M,K] row-major (opt. row-gather),
// B fp32 [K,N] row-major converted to bf16 + transposed into LDS.
template<bool GATHER>
__device__ __forceinline__ void gemm_core(
    const u16* __restrict__ A, int lda, const int* __restrict__ rowlist,
    const float* __restrict__ B, int ldb, int K, int row0, int col0,
    u16* As, u16* Bt, f32x4 acc[4][4])
{
  const int tid = threadIdx.x;
  const int lane = tid & 63;
  const int w = tid >> 6;
  const int wr = w >> 1, wc = w & 1;
  const int l15 = lane & 15, l4 = lane >> 4;

  const int ar = tid >> 1;            // A row 0..127
  const int ac = (tid & 1) * 16;      // A col 0 or 16
  long arow;
  if constexpr (GATHER) arow = rowlist[row0 + ar];
  else                  arow = row0 + ar;
  const u16* Ap = A + arow * (long)lda + ac;
  u16* AsW = As + ar * 40 + ac;

  const int bn  = tid & 127;          // B col 0..127
  const int bk0 = (tid >> 7) * 16;    // B k half
  const float* Bp = B + (long)bk0 * ldb + col0 + bn;
  u16* BtW = Bt + bn * 40 + bk0;

  for (int k0 = 0; k0 < K; k0 += 32){
    const short8 a0 = *(const short8*)(Ap + k0);
    const short8 a1 = *(const short8*)(Ap + k0 + 8);
    float bv[16];
#pragma unroll
    for (int kk = 0; kk < 16; ++kk)
      bv[kk] = Bp[(long)(k0 + kk) * ldb];
    *(short8*)AsW = a0;
    *(short8*)(AsW + 8) = a1;
    short8 b0, b1;
#pragma unroll
    for (int kk = 0; kk < 8; ++kk){
      b0[kk] = (short)f2bf(bv[kk]);
      b1[kk] = (short)f2bf(bv[8 + kk]);
    }
    *(short8*)BtW = b0;
    *(short8*)(BtW + 8) = b1;
    __syncthreads();
    short8 aF[4], bF[4];
#pragma unroll
    for (int mi = 0; mi < 4; ++mi)
      aF[mi] = *(const short8*)(As + (wr*64 + mi*16 + l15)*40 + l4*8);
#pragma unroll
    for (int ni = 0; ni < 4; ++ni)
      bF[ni] = *(const short8*)(Bt + (wc*64 + ni*16 + l15)*40 + l4*8);
#pragma unroll
    for (int mi = 0; mi < 4; ++mi)
#pragma unroll
      for (int ni = 0; ni < 4; ++ni)
        acc[mi][ni] = __builtin_amdgcn_mfma_f32_16x16x32_bf16(aF[mi], bF[ni], acc[mi][ni], 0, 0, 0);
    __syncthreads();
  }
}

#define GEMM_EPI_VARS \
  const int lane = threadIdx.x & 63; \
  const int wv = threadIdx.x >> 6;   \
  const int wr = wv >> 1, wc = wv & 1; \
  const int l15 = lane & 15, l4 = lane >> 4;

// ---------------------------------------------------------------- kernels
__global__ __launch_bounds__(256) void k_init(int* expert_tok, int* slot_of){
  const int i = blockIdx.x * 256 + threadIdx.x;   // 0..4095
  expert_tok[i] = 0;
  slot_of[i] = -1;
}

__global__ __launch_bounds__(256) void k_sincos(float* __restrict__ st, float* __restrict__ ct){
  const int idx = blockIdx.x * 256 + threadIdx.x; // 0..32767
  const int t = idx >> 5, i = idx & 31;
  const float inv = expf((float)(2 * i) * (-0.14391157f)); // -ln(10000)/64
  const float ang = (float)t * inv;
  st[idx] = sinf(ang);
  ct[idx] = cosf(ang);
}

__global__ __launch_bounds__(256) void k_ln(const float* __restrict__ x,
    const float* __restrict__ g, const float* __restrict__ bb,
    u16* __restrict__ hb, float* __restrict__ hf)
{
  const int row = blockIdx.x, tid = threadIdx.x;
  const int w = tid >> 6, lane = tid & 63;
  const float4 xv = *(const float4*)(x + (long)row*DD + tid*4);
  __shared__ float red[8];
  float s = xv.x + xv.y + xv.z + xv.w;
  s = waveRedSum(s);
  if (lane == 0) red[w] = s;
  __syncthreads();
  const float mean = (red[0]+red[1]+red[2]+red[3]) * (1.f/1024.f);
  const float d0 = xv.x-mean, d1 = xv.y-mean, d2 = xv.z-mean, d3 = xv.w-mean;
  float vs = d0*d0 + d1*d1 + d2*d2 + d3*d3;
  vs = waveRedSum(vs);
  if (lane == 0) red[4+w] = vs;
  __syncthreads();
  const float var = (red[4]+red[5]+red[6]+red[7]) * (1.f/1024.f);
  const float inv = rsqrtf(var + 1e-5f);
  const int c = tid*4;
  const float y0 = d0*inv*g[c+0] + bb[c+0];
  const float y1 = d1*inv*g[c+1] + bb[c+1];
  const float y2 = d2*inv*g[c+2] + bb[c+2];
  const float y3 = d3*inv*g[c+3] + bb[c+3];
  short4v p;
  p[0] = (short)f2bf(y0); p[1] = (short)f2bf(y1);
  p[2] = (short)f2bf(y2); p[3] = (short)f2bf(y3);
  *(short4v*)(hb + (long)row*DD + c) = p;
  if (hf){
    float4 o; o.x = y0; o.y = y1; o.z = y2; o.w = y3;
    *(float4*)(hf + (long)row*DD + c) = o;
  }
}

__global__ __launch_bounds__(256) void k_gemm_qkv(const u16* __restrict__ h1,
    const float* __restrict__ wq, u16* __restrict__ qkv)
{
  __shared__ u16 As[128*40], Bt[128*40];
  const int id = blockIdx.x;
  const int pcol = id % 24, mt = id / 24;
  const int row0 = mt*128, col0 = pcol*128;
  const f32x4 fz = {0.f,0.f,0.f,0.f};
  f32x4 acc[4][4];
#pragma unroll
  for (int i = 0; i < 4; ++i)
#pragma unroll
    for (int j = 0; j < 4; ++j) acc[i][j] = fz;
  gemm_core<false>(h1, DD, nullptr, wq, 3*DD, DD, row0, col0, As, Bt, acc);
  GEMM_EPI_VARS
#pragma unroll
  for (int mi = 0; mi < 4; ++mi)
#pragma unroll
    for (int ni = 0; ni < 4; ++ni)
#pragma unroll
      for (int r = 0; r < 4; ++r){
        const int rr = row0 + wr*64 + mi*16 + l4*4 + r;
        const int cc = col0 + wc*64 + ni*16 + l15;
        qkv[(long)rr*(3*DD) + cc] = f2bf(acc[mi][ni][r]);
      }
}

__global__ __launch_bounds__(256) void k_rope(const u16* __restrict__ qkv,
    const float* __restrict__ st, const float* __restrict__ ct,
    u16* __restrict__ q_r, u16* __restrict__ k_r, u16* __restrict__ v_t)
{
  __shared__ u16 vt[64*72];
  const int tid = threadIdx.x;
  const int bh = blockIdx.y, bidx = bh >> 4, h = bh & 15;
  const int t0 = blockIdx.x * 64;
  const int tl = tid >> 2, qq = tid & 3;
  const int t = t0 + tl;
  const long row = (long)(bidx*TB + t) * (3*DD);
  const int i0 = qq * 8;
  { // q (scaled by 1/sqrt(64))
    const short8 v1 = *(const short8*)(qkv + row + h*64 + i0);
    const short8 v2 = *(const short8*)(qkv + row + h*64 + 32 + i0);
    short8 o1, o2;
#pragma unroll
    for (int j = 0; j < 8; ++j){
      const float f1 = bf2f((u16)v1[j]), f2 = bf2f((u16)v2[j]);
      const float sv = st[t*32 + i0 + j], cv = ct[t*32 + i0 + j];
      o1[j] = (short)f2bf((f1*cv - f2*sv) * 0.125f);
      o2[j] = (short)f2bf((f2*cv + f1*sv) * 0.125f);
    }
    u16* qp = q_r + ((long)bh*TB + t)*64 + i0;
    *(short8*)qp = o1; *(short8*)(qp + 32) = o2;
  }
  { // k
    const short8 v1 = *(const short8*)(qkv + row + DD + h*64 + i0);
    const short8 v2 = *(const short8*)(qkv + row + DD + h*64 + 32 + i0);
    short8 o1, o2;
#pragma unroll
    for (int j = 0; j < 8; ++j){
      const float f1 = bf2f((u16)v1[j]), f2 = bf2f((u16)v2[j]);
      const float sv = st[t*32 + i0 + j], cv = ct[t*32 + i0 + j];
      o1[j] = (short)f2bf(f1*cv - f2*sv);
      o2[j] = (short)f2bf(f2*cv + f1*sv);
    }
    u16* kp = k_r + ((long)bh*TB + t)*64 + i0;
    *(short8*)kp = o1; *(short8*)(kp + 32) = o2;
  }
  { // v transpose to [bh][dh][t]
    const short8 w0 = *(const short8*)(qkv + row + 2*DD + h*64 + qq*16);
    const short8 w1 = *(const short8*)(qkv + row + 2*DD + h*64 + qq*16 + 8);
#pragma unroll
    for (int j = 0; j < 8; ++j){
      vt[(qq*16 + j)*72 + tl]     = (u16)w0[j];
      vt[(qq*16 + 8 + j)*72 + tl] = (u16)w1[j];
    }
  }
  __syncthreads();
  {
    const int dh = tid >> 2, seg = tid & 3;
    const short8 r0 = *(const short8*)(vt + dh*72 + seg*16);
    const short8 r1 = *(const short8*)(vt + dh*72 + seg*16 + 8);
    u16* vp = v_t + ((long)bh*64 + dh)*TB + t0 + seg*16;
    *(short8*)vp = r0; *(short8*)(vp + 8) = r1;
  }
}

// flash attention: one wave = 16 q rows; per block 4 waves, 64 q rows.
__global__ __launch_bounds__(256) void k_attn(const u16* __restrict__ q_r,
    const u16* __restrict__ k_r, const u16* __restrict__ v_t, u16* __restrict__ ao)
{
  __shared__ u16 P_lds[4][16*80];
  const int tid = threadIdx.x;
  const int w = tid >> 6, lane = tid & 63;
  const int l15 = lane & 15, l4 = lane >> 4;
  const int bh = blockIdx.y, b = bh >> 4, h = bh & 15;
  const int q0 = blockIdx.x*64 + w*16;
  u16* P = &P_lds[w][0];
  const long qoff = ((long)bh*TB + q0 + l15)*64 + l4*8;
  const short8 Qf0 = *(const short8*)(q_r + qoff);
  const short8 Qf1 = *(const short8*)(q_r + qoff + 32);
  const f32x4 fz = {0.f,0.f,0.f,0.f};
  f32x4 O[4];
  float m[4], L[4];
#pragma unroll
  for (int i = 0; i < 4; ++i){ O[i] = fz; m[i] = -1e30f; L[i] = 0.f; }
  const int ntiles = blockIdx.x + 1;
  for (int stt = 0; stt < ntiles; ++stt){
    const int s0 = stt*64;
    f32x4 S[4];
#pragma unroll
    for (int sj = 0; sj < 4; ++sj){
      const u16* kp = k_r + ((long)bh*TB + s0 + sj*16 + l15)*64 + l4*8;
      const short8 kf0 = *(const short8*)kp;
      const short8 kf1 = *(const short8*)(kp + 32);
      f32x4 z = fz;
      z = __builtin_amdgcn_mfma_f32_16x16x32_bf16(Qf0, kf0, z, 0, 0, 0);
      z = __builtin_amdgcn_mfma_f32_16x16x32_bf16(Qf1, kf1, z, 0, 0, 0);
      S[sj] = z;
    }
    if (stt == blockIdx.x){
#pragma unroll
      for (int sj = 0; sj < 4; ++sj)
#pragma unroll
        for (int r = 0; r < 4; ++r){
          const int sc = s0 + sj*16 + l15;
          const int qr = q0 + l4*4 + r;
          if (sc > qr) S[sj][r] = -1e30f;
        }
    }
    float vm[4];
#pragma unroll
    for (int r = 0; r < 4; ++r){
      vm[r] = fmaxf(fmaxf(S[0][r], S[1][r]), fmaxf(S[2][r], S[3][r]));
      vm[r] = fmaxf(vm[r], __shfl_xor(vm[r], 1));
      vm[r] = fmaxf(vm[r], __shfl_xor(vm[r], 2));
      vm[r] = fmaxf(vm[r], __shfl_xor(vm[r], 4));
      vm[r] = fmaxf(vm[r], __shfl_xor(vm[r], 8));
    }
    float corr[4], ls[4];
#pragma unroll
    for (int r = 0; r < 4; ++r){
      const float mn = fmaxf(m[r], vm[r]);
      corr[r] = __expf(m[r] - mn);
      m[r] = mn;
      ls[r] = 0.f;
    }
#pragma unroll
    for (int sj = 0; sj < 4; ++sj)
#pragma unroll
      for (int r = 0; r < 4; ++r){
        const float pv = __expf(S[sj][r] - m[r]);
        S[sj][r] = pv;
        ls[r] += pv;
      }
#pragma unroll
    for (int r = 0; r < 4; ++r){
      ls[r] += __shfl_xor(ls[r], 1);
      ls[r] += __shfl_xor(ls[r], 2);
      ls[r] += __shfl_xor(ls[r], 4);
      ls[r] += __shfl_xor(ls[r], 8);
      L[r] = L[r]*corr[r] + ls[r];
    }
#pragma unroll
    for (int nj = 0; nj < 4; ++nj)
#pragma unroll
      for (int r = 0; r < 4; ++r)
        O[nj][r] *= corr[r];
#pragma unroll
    for (int sj = 0; sj < 4; ++sj)
#pragma unroll
      for (int r = 0; r < 4; ++r)
        P[(l4*4 + r)*80 + sj*16 + l15] = f2bf(S[sj][r]);
    __syncthreads();
    const short8 pf0 = *(const short8*)(P + l15*80 + l4*8);
    const short8 pf1 = *(const short8*)(P + l15*80 + 32 + l4*8);
#pragma unroll
    for (int nj = 0; nj < 4; ++nj){
      const u16* vp = v_t + ((long)bh*64 + nj*16 + l15)*TB + s0 + l4*8;
      const short8 vf0 = *(const short8*)vp;
      const short8 vf1 = *(const short8*)(vp + 32);
      O[nj] = __builtin_amdgcn_mfma_f32_16x16x32_bf16(pf0, vf0, O[nj], 0, 0, 0);
      O[nj] = __builtin_amdgcn_mfma_f32_16x16x32_bf16(pf1, vf1, O[nj], 0, 0, 0);
    }
    __syncthreads();
  }
#pragma unroll
  for (int nj = 0; nj < 4; ++nj)
#pragma unroll
    for (int r = 0; r < 4; ++r){
      const float val = O[nj][r] / L[r];
      const long orow = (long)b*TB + q0 + l4*4 + r;
      ao[orow*DD + h*64 + nj*16 + l15] = f2bf(val);
    }
}

__global__ __launch_bounds__(256) void k_gemm_proj(const u16* __restrict__ ao,
    const float* __restrict__ wp, const float* __restrict__ x, float* __restrict__ out)
{
  __shared__ u16 As[128*40], Bt[128*40];
  const int id = blockIdx.x;
  const int pcol = id % 8, mt = id / 8;
  const int row0 = mt*128, col0 = pcol*128;
  const f32x4 fz = {0.f,0.f,0.f,0.f};
  f32x4 acc[4][4];
#pragma unroll
  for (int i = 0; i < 4; ++i)
#pragma unroll
    for (int j = 0; j < 4; ++j) acc[i][j] = fz;
  gemm_core<false>(ao, DD, nullptr, wp, DD, DD, row0, col0, As, Bt, acc);
  GEMM_EPI_VARS
#pragma unroll
  for (int mi = 0; mi < 4; ++mi)
#pragma unroll
    for (int ni = 0; ni < 4; ++ni)
#pragma unroll
      for (int r = 0; r < 4; ++r){
        const int rr = row0 + wr*64 + mi*16 + l4*4 + r;
        const int cc = col0 + wc*64 + ni*16 + l15;
        out[(long)rr*DD + cc] = x[(long)rr*DD + cc] + acc[mi][ni][r];
      }
}

__global__ __launch_bounds__(256) void k_router(const float* __restrict__ h2f,
    const float* __restrict__ w_rl, const float* __restrict__ b_rl,
    const float* __restrict__ w_rn, const float* __restrict__ b_rn,
    const float* __restrict__ noise, int2* __restrict__ tok_e, float2* __restrict__ tok_g)
{
  const int tok = blockIdx.x, tid = threadIdx.x;
  const int w = tid >> 6, lane = tid & 63;
  float accl[8] = {0,0,0,0,0,0,0,0};
  float accn[8] = {0,0,0,0,0,0,0,0};
  const float4 hq = *(const float4*)(h2f + (long)tok*DD + tid*4);
  const float hv[4] = {hq.x, hq.y, hq.z, hq.w};
#pragma unroll
  for (int j = 0; j < 4; ++j){
    const int k = tid*4 + j;
    const float4 a = *(const float4*)(w_rl + k*8);
    const float4 b = *(const float4*)(w_rl + k*8 + 4);
    accl[0] += hv[j]*a.x; accl[1] += hv[j]*a.y; accl[2] += hv[j]*a.z; accl[3] += hv[j]*a.w;
    accl[4] += hv[j]*b.x; accl[5] += hv[j]*b.y; accl[6] += hv[j]*b.z; accl[7] += hv[j]*b.w;
    const float4 c = *(const float4*)(w_rn + k*8);
    const float4 d = *(const float4*)(w_rn + k*8 + 4);
    accn[0] += hv[j]*c.x; accn[1] += hv[j]*c.y; accn[2] += hv[j]*c.z; accn[3] += hv[j]*c.w;
    accn[4] += hv[j]*d.x; accn[5] += hv[j]*d.y; accn[6] += hv[j]*d.z; accn[7] += hv[j]*d.w;
  }
  __shared__ float red[4][16];
#pragma unroll
  for (int e = 0; e < 8; ++e){ accl[e] = waveRedSum(accl[e]); accn[e] = waveRedSum(accn[e]); }
  if (lane == 0){
#pragma unroll
    for (int e = 0; e < 8; ++e){ red[w][e] = accl[e]; red[w][8+e] = accn[e]; }
  }
  __syncthreads();
  if (tid == 0){
    float nv[8];
#pragma unroll
    for (int e = 0; e < 8; ++e){
      const float lr = red[0][e]+red[1][e]+red[2][e]+red[3][e] + b_rl[e];
      const float lnv = red[0][8+e]+red[1][8+e]+red[2][8+e]+red[3][8+e] + b_rn[e];
      const float sp = fmaxf(lnv, 0.f) + log1pf(expf(-fabsf(lnv)));
      nv[e] = lr + noise[tok*8 + e] * sp;
    }
    int bi = 0; float bvv = nv[0];
#pragma unroll
    for (int e = 1; e < 8; ++e) if (nv[e] > bvv){ bvv = nv[e]; bi = e; }
    int si = (bi == 0) ? 1 : 0;
    float sv = nv[si];
#pragma unroll
    for (int e = 0; e < 8; ++e) if (e != bi && nv[e] > sv){ sv = nv[e]; si = e; }
    const float tt = expf(sv - bvv);
    tok_e[tok] = make_int2(bi, si);
    tok_g[tok] = make_float2(1.f/(1.f + tt), tt/(1.f + tt));
  }
}

__global__ __launch_bounds__(256) void k_assign(const int2* __restrict__ tok_e,
    int* __restrict__ expert_tok, int* __restrict__ slot_of)
{
  const int e = blockIdx.x, tid = threadIdx.x;
  __shared__ int cnt[256];
  int which[8]; int c = 0;
  const int t0 = tid * 8;
#pragma unroll
  for (int j = 0; j < 8; ++j){
    const int2 te = tok_e[t0 + j];
    int wj = -1;
    if (te.x == e) wj = 0; else if (te.y == e) wj = 1;
    which[j] = wj;
    c += (wj >= 0) ? 1 : 0;
  }
  cnt[tid] = c;
  __syncthreads();
  if (tid == 0){
    int run = 0;
    for (int i = 0; i < 256; ++i){ const int v = cnt[i]; cnt[i] = run; run += v; }
  }
  __syncthreads();
  int pos = cnt[tid];
#pragma unroll
  for (int j = 0; j < 8; ++j){
    if (which[j] >= 0){
      if (pos < CAPN){
        expert_tok[e*CAPN + pos] = t0 + j;
        slot_of[(t0 + j)*2 + which[j]] = e*CAPN + pos;
      }
      ++pos;
    }
  }
}

__global__ __launch_bounds__(256) void k_ffn1(const u16* __restrict__ h2b,
    const float* __restrict__ w1, const float* __restrict__ b1,
    const int* __restrict__ expert_tok, u16* __restrict__ act)
{
  __shared__ u16 As[128*40], Bt[128*40];
  const int z = blockIdx.z;
  const int id = blockIdx.x;
  const int pcol = id % 32, mt = id / 32;
  const int row0 = mt*128, col0 = pcol*128;
  const f32x4 fz = {0.f,0.f,0.f,0.f};
  f32x4 acc[4][4];
#pragma unroll
  for (int i = 0; i < 4; ++i)
#pragma unroll
    for (int j = 0; j < 4; ++j) acc[i][j] = fz;
  gemm_core<true>(h2b, DD, expert_tok + z*CAPN, w1 + (long)z*DD*DFF, DFF, DD,
                  row0, col0, As, Bt, acc);
  GEMM_EPI_VARS
#pragma unroll
  for (int mi = 0; mi < 4; ++mi)
#pragma unroll
    for (int ni = 0; ni < 4; ++ni)
#pragma unroll
      for (int r = 0; r < 4; ++r){
        const int rr = row0 + wr*64 + mi*16 + l4*4 + r;
        const int cc = col0 + wc*64 + ni*16 + l15;
        const float val = fmaxf(acc[mi][ni][r] + b1[z*DFF + cc], 0.f);
        act[((long)z*CAPN + rr)*DFF + cc] = f2bf(val);
      }
}

__global__ __launch_bounds__(256) void k_ffn2(const u16* __restrict__ act,
    const float* __restrict__ w2, const float* __restrict__ b2, float* __restrict__ out_e)
{
  __shared__ u16 As[128*40], Bt[128*40];
  const int z = blockIdx.z;
  const int id = blockIdx.x;
  const int pcol = id % 8, mt = id / 8;
  const int row0 = mt*128, col0 = pcol*128;
  const f32x4 fz = {0.f,0.f,0.f,0.f};
  f32x4 acc[4][4];
#pragma unroll
  for (int i = 0; i < 4; ++i)
#pragma unroll
    for (int j = 0; j < 4; ++j) acc[i][j] = fz;
  gemm_core<false>(act + (long)z*CAPN*DFF, DFF, nullptr, w2 + (long)z*DFF*DD, DD, DFF,
                   row0, col0, As, Bt, acc);
  GEMM_EPI_VARS
#pragma unroll
  for (int mi = 0; mi < 4; ++mi)
#pragma unroll
    for (int ni = 0; ni < 4; ++ni)
#pragma unroll
      for (int r = 0; r < 4; ++r){
        const int rr = row0 + wr*64 + mi*16 + l4*4 + r;
        const int cc = col0 + wc*64 + ni*16 + l15;
        out_e[((long)z*CAPN + rr)*DD + cc] = acc[mi][ni][r] + b2[z*DD + cc];
      }
}

__global__ __launch_bounds__(256) void k_combine(float* __restrict__ out,
    const int* __restrict__ slot_of, const float2* __restrict__ tok_g,
    const float* __restrict__ out_e)
{
  const int tok = blockIdx.x, c = threadIdx.x * 4;
  float4 o = *(float4*)(out + (long)tok*DD + c);
  const int s0 = slot_of[tok*2], s1 = slot_of[tok*2 + 1];
  const float2 g = tok_g[tok];
  if (s0 >= 0){
    const float4 v = *(const float4*)(out_e + (long)s0*DD + c);
    o.x += g.x*v.x; o.y += g.x*v.y; o.z += g.x*v.z; o.w += g.x*v.w;
  }
  if (s1 >= 0){
    const float4 v = *(const float4*)(out_e + (long)s1*DD + c);
    o.x += g.y*v.x; o.y += g.y*v.y; o.z += g.y*v.z; o.w += g.y*v.w;
  }
  *(float4*)(out + (long)tok*DD + c) = o;
}

// ---------------------------------------------------------------- launcher
extern "C" void kernel_launch(void* const* d_in, const int* in_sizes, int n_in,
                              void* d_out, int out_size, void* d_ws, size_t ws_size,
                              hipStream_t stream)
{
  (void)in_sizes; (void)n_in; (void)out_size; (void)ws_size;
  const float* x      = (const float*)d_in[0];
  const float* noise  = (const float*)d_in[1];
  const float* ln1_g  = (const float*)d_in[2];
  const float* ln1_b  = (const float*)d_in[3];
  const float* ln2_g  = (const float*)d_in[4];
  const float* ln2_b  = (const float*)d_in[5];
  const float* w_qkv  = (const float*)d_in[6];
  const float* w_proj = (const float*)d_in[7];
  const float* w_rl   = (const float*)d_in[8];
  const float* b_rl   = (const float*)d_in[9];
  const float* w_rn   = (const float*)d_in[10];
  const float* b_rn   = (const float*)d_in[11];
  const float* w1     = (const float*)d_in[12];
  const float* b1     = (const float*)d_in[13];
  const float* w2     = (const float*)d_in[14];
  const float* b2     = (const float*)d_in[15];
  float* out = (float*)d_out;

  char* p = (char*)d_ws;
  auto carve = [&](size_t bytes) -> void* {
    void* r = (void*)p;
    p += (bytes + 255) & ~(size_t)255;
    return r;
  };
  float* sin_t      = (float*)carve((size_t)TB*32*4);
  float* cos_t      = (float*)carve((size_t)TB*32*4);
  u16*   h1         = (u16*)  carve((size_t)NTOK*DD*2);
  u16*   qkv        = (u16*)  carve((size_t)NTOK*3*DD*2);
  u16*   q_r        = (u16*)  carve((size_t)NTOK*DD*2);
  u16*   k_r        = (u16*)  carve((size_t)NTOK*DD*2);
  u16*   v_t        = (u16*)  carve((size_t)NTOK*DD*2);
  u16*   ao         = (u16*)  carve((size_t)NTOK*DD*2);
  u16*   h2b        = (u16*)  carve((size_t)NTOK*DD*2);
  float* h2f        = (float*)carve((size_t)NTOK*DD*4);
  int2*  tok_e      = (int2*) carve((size_t)NTOK*8);
  float2* tok_g     = (float2*)carve((size_t)NTOK*8);
  int*   slot_of    = (int*)  carve((size_t)NTOK*2*4);
  int*   expert_tok = (int*)  carve((size_t)NEXPERT*CAPN*4);
  u16*   act        = (u16*)  carve((size_t)NEXPERT*CAPN*DFF*2);
  float* out_e      = (float*)carve((size_t)NEXPERT*CAPN*DD*4);

  k_init   <<<16, 256, 0, stream>>>(expert_tok, slot_of);
  k_sincos <<<128, 256, 0, stream>>>(sin_t, cos_t);
  k_ln     <<<NTOK, 256, 0, stream>>>(x, ln1_g, ln1_b, h1, nullptr);
  k_gemm_qkv<<<384, 256, 0, stream>>>(h1, w_qkv, qkv);
  k_rope   <<<dim3(16, 32), 256, 0, stream>>>(qkv, sin_t, cos_t, q_r, k_r, v_t);
  k_attn   <<<dim3(16, 32), 256, 0, stream>>>(q_r, k_r, v_t, ao);
  k_gemm_proj<<<128, 256, 0, stream>>>(ao, w_proj, x, out);
  k_ln     <<<NTOK, 256, 0, stream>>>(out, ln2_g, ln2_b, h2b, h2f);
  k_router <<<NTOK, 256, 0, stream>>>(h2f, w_rl, b_rl, w_rn, b_rn, noise, tok_e, tok_g);
  k_assign <<<NEXPERT, 256, 0, stream>>>(tok_e, expert_tok, slot_of);
  k_ffn1   <<<dim3(128, 1, 8), 256, 0, stream>>>(h2b, w1, b1, expert_tok, act);
  k_ffn2   <<<dim3(32, 1, 8), 256, 0, stream>>>(act, w2, b2, out_e);
  k_combine<<<NTOK, 256, 0, stream>>>(out, slot_of, tok_g, out_e);
}

// Round 2
// 448.319 us; speedup vs baseline: 1.0541x; 1.0541x over previous
//
#include <hip/hip_runtime.h>

// MoE transformer block: LN1 -> QKV -> RoPE -> causal flash attn -> proj+res
// -> LN2 -> noisy top-2 router (cap 512) -> expert FFN (split-K) -> combine.
// Weights pre-converted fp32[K,N] -> bf16[N,K] once per call; all GEMMs use
// m97 structure: global_load_lds dwordx4 staging, 128^2 tile, 16x16x32 MFMA.

#define TB 1024   // T
#define DD 1024   // D
#define NTOK 2048 // B*T
#define NEXPERT 8
#define CAPN 512
#define DFF 4096

typedef __attribute__((ext_vector_type(4))) float f32x4;
typedef __attribute__((ext_vector_type(8))) short short8;
typedef __attribute__((ext_vector_type(4))) short short4v;
typedef unsigned short u16;
typedef unsigned int u32;

__device__ __forceinline__ u16 f2bf(float f){
  union { float f; u32 u; } v; v.f = f;
  u32 u = v.u;
  u32 r = (u + 0x7fffu + ((u >> 16) & 1u)) >> 16;
  return (u16)r;
}
__device__ __forceinline__ float bf2f(u16 b){
  union { u32 u; float f; } v; v.u = ((u32)b) << 16;
  return v.f;
}
__device__ __forceinline__ float waveRedSum(float v){
#pragma unroll
  for (int o = 1; o < 64; o <<= 1) v += __shfl_xor(v, o);
  return v;
}

// async global->LDS, 16B per lane, wave-uniform LDS base + lane*16
__device__ __forceinline__ void gl16(const u16* g, u16* l){
  __builtin_amdgcn_global_load_lds(
    (const __attribute__((address_space(1))) u32*)g,
    (__attribute__((address_space(3))) u32*)l, 16, 0, 0);
}

// ------------------------------------------------------------- weight prep
// src fp32 [K][N] -> dst bf16 [N][K]; 64x64 tiles; blockIdx.z = expert.
__global__ __launch_bounds__(256) void k_wt(const float* __restrict__ src,
    u16* __restrict__ dst, int K, int N)
{
  __shared__ float tile[64][65];
  const long zoff = (long)blockIdx.z * K * N;
  const int k0 = blockIdx.y * 64, n0 = blockIdx.x * 64;
  const int tid = threadIdx.x;
  const int r  = tid >> 2;
  const int c4 = (tid & 3) * 16;
#pragma unroll
  for (int j = 0; j < 4; ++j){
    const float4 v = *(const float4*)(src + zoff + (long)(k0 + r)*N + n0 + c4 + j*4);
    tile[r][c4 + j*4 + 0] = v.x;
    tile[r][c4 + j*4 + 1] = v.y;
    tile[r][c4 + j*4 + 2] = v.z;
    tile[r][c4 + j*4 + 3] = v.w;
  }
  __syncthreads();
  const int n  = tid >> 2;
  const int ks = (tid & 3) * 16;
  short8 o0, o1;
#pragma unroll
  for (int j = 0; j < 8; ++j){
    o0[j] = (short)f2bf(tile[ks + j][n]);
    o1[j] = (short)f2bf(tile[ks + 8 + j][n]);
  }
  u16* dp = dst + zoff + (long)(n0 + n)*K + k0 + ks;
  *(short8*)dp = o0;
  *(short8*)(dp + 8) = o1;
}

// ---------------------------------------------------------------- GEMM core
// C 128x128 tile, 4 waves 2x2, A bf16 [M,K] (opt row-gather), B bf16 [N,K].
// BK=32. global_load_lds staging: 8 chunks of (16 rows x 64B) per operand;
// wave w issues chunks {w, w+4} for A and B.
template<bool GATHER>
__device__ __forceinline__ void gemm_core2(
    const u16* __restrict__ A, int lda, const int* __restrict__ rowlist,
    const u16* __restrict__ Bt, int ldb, int K, int kstart, int row0, int col0,
    u16* As, u16* Bs, f32x4 acc[4][4])
{
  const int tid = threadIdx.x;
  const int lane = tid & 63;
  const int w = tid >> 6;
  const int wr = w >> 1, wc = w & 1;
  const int l15 = lane & 15, l4 = lane >> 4;
  const int lr = lane >> 2;        // row within 16-row chunk
  const int lc = (lane & 3) * 8;   // u16 offset within 64B row

  const int c0 = w, c1 = w + 4;
  long ar0, ar1;
  if constexpr (GATHER){
    ar0 = rowlist[row0 + c0*16 + lr];
    ar1 = rowlist[row0 + c1*16 + lr];
  } else {
    ar0 = row0 + c0*16 + lr;
    ar1 = row0 + c1*16 + lr;
  }
  const u16* Ap0 = A + ar0*(long)lda + kstart + lc;
  const u16* Ap1 = A + ar1*(long)lda + kstart + lc;
  const u16* Bp0 = Bt + (long)(col0 + c0*16 + lr)*ldb + kstart + lc;
  const u16* Bp1 = Bt + (long)(col0 + c1*16 + lr)*ldb + kstart + lc;
  u16* AsD0 = As + c0*512;
  u16* AsD1 = As + c1*512;
  u16* BsD0 = Bs + c0*512;
  u16* BsD1 = Bs + c1*512;

  for (int k0 = 0; k0 < K; k0 += 32){
    gl16(Ap0 + k0, AsD0);
    gl16(Ap1 + k0, AsD1);
    gl16(Bp0 + k0, BsD0);
    gl16(Bp1 + k0, BsD1);
    __syncthreads();
    short8 aF[4], bF[4];
#pragma unroll
    for (int mi = 0; mi < 4; ++mi)
      aF[mi] = *(const short8*)(As + (wr*64 + mi*16 + l15)*32 + l4*8);
#pragma unroll
    for (int ni = 0; ni < 4; ++ni)
      bF[ni] = *(const short8*)(Bs + (wc*64 + ni*16 + l15)*32 + l4*8);
#pragma unroll
    for (int mi = 0; mi < 4; ++mi)
#pragma unroll
      for (int ni = 0; ni < 4; ++ni)
        acc[mi][ni] = __builtin_amdgcn_mfma_f32_16x16x32_bf16(aF[mi], bF[ni], acc[mi][ni], 0, 0, 0);
    __syncthreads();
  }
}

#define GEMM_PRE \
  __shared__ u16 As[128*32], Bs[128*32]; \
  const f32x4 fz = {0.f,0.f,0.f,0.f}; \
  f32x4 acc[4][4]; \
  _Pragma("unroll") for (int i = 0; i < 4; ++i) \
  _Pragma("unroll") for (int j = 0; j < 4; ++j) acc[i][j] = fz;

#define GEMM_EPI_VARS \
  const int lane = threadIdx.x & 63; \
  const int wv = threadIdx.x >> 6;   \
  const int wr = wv >> 1, wc = wv & 1; \
  const int l15 = lane & 15, l4 = lane >> 4;

// ---------------------------------------------------------------- kernels
__global__ __launch_bounds__(256) void k_init(int* expert_tok, int* slot_of){
  const int i = blockIdx.x * 256 + threadIdx.x;
  expert_tok[i] = 0;
  slot_of[i] = -1;
}

__global__ __launch_bounds__(256) void k_sincos(float* __restrict__ st, float* __restrict__ ct){
  const int idx = blockIdx.x * 256 + threadIdx.x;
  const int t = idx >> 5, i = idx & 31;
  const float inv = expf((float)(2 * i) * (-0.14391157f));
  const float ang = (float)t * inv;
  st[idx] = sinf(ang);
  ct[idx] = cosf(ang);
}

__global__ __launch_bounds__(256) void k_ln(const float* __restrict__ x,
    const float* __restrict__ g, const float* __restrict__ bb,
    u16* __restrict__ hb, float* __restrict__ hf)
{
  const int row = blockIdx.x, tid = threadIdx.x;
  const int w = tid >> 6, lane = tid & 63;
  const float4 xv = *(const float4*)(x + (long)row*DD + tid*4);
  __shared__ float red[8];
  float s = xv.x + xv.y + xv.z + xv.w;
  s = waveRedSum(s);
  if (lane == 0) red[w] = s;
  __syncthreads();
  const float mean = (red[0]+red[1]+red[2]+red[3]) * (1.f/1024.f);
  const float d0 = xv.x-mean, d1 = xv.y-mean, d2 = xv.z-mean, d3 = xv.w-mean;
  float vs = d0*d0 + d1*d1 + d2*d2 + d3*d3;
  vs = waveRedSum(vs);
  if (lane == 0) red[4+w] = vs;
  __syncthreads();
  const float var = (red[4]+red[5]+red[6]+red[7]) * (1.f/1024.f);
  const float inv = rsqrtf(var + 1e-5f);
  const int c = tid*4;
  const float y0 = d0*inv*g[c+0] + bb[c+0];
  const float y1 = d1*inv*g[c+1] + bb[c+1];
  const float y2 = d2*inv*g[c+2] + bb[c+2];
  const float y3 = d3*inv*g[c+3] + bb[c+3];
  short4v p;
  p[0] = (short)f2bf(y0); p[1] = (short)f2bf(y1);
  p[2] = (short)f2bf(y2); p[3] = (short)f2bf(y3);
  *(short4v*)(hb + (long)row*DD + c) = p;
  if (hf){
    float4 o; o.x = y0; o.y = y1; o.z = y2; o.w = y3;
    *(float4*)(hf + (long)row*DD + c) = o;
  }
}

__global__ __launch_bounds__(256) void k_gemm_qkv(const u16* __restrict__ h1,
    const u16* __restrict__ wqT, u16* __restrict__ qkv)
{
  GEMM_PRE
  const int id = blockIdx.x;
  const int pcol = id % 24, mt = id / 24;
  const int row0 = mt*128, col0 = pcol*128;
  gemm_core2<false>(h1, DD, nullptr, wqT, DD, DD, 0, row0, col0, As, Bs, acc);
  GEMM_EPI_VARS
#pragma unroll
  for (int mi = 0; mi < 4; ++mi)
#pragma unroll
    for (int ni = 0; ni < 4; ++ni)
#pragma unroll
      for (int r = 0; r < 4; ++r){
        const int rr = row0 + wr*64 + mi*16 + l4*4 + r;
        const int cc = col0 + wc*64 + ni*16 + l15;
        qkv[(long)rr*(3*DD) + cc] = f2bf(acc[mi][ni][r]);
      }
}

__global__ __launch_bounds__(256) void k_rope(const u16* __restrict__ qkv,
    const float* __restrict__ st, const float* __restrict__ ct,
    u16* __restrict__ q_r, u16* __restrict__ k_r, u16* __restrict__ v_t)
{
  __shared__ u16 vt[64*72];
  const int tid = threadIdx.x;
  const int bh = blockIdx.y, bidx = bh >> 4, h = bh & 15;
  const int t0 = blockIdx.x * 64;
  const int tl = tid >> 2, qq = tid & 3;
  const int t = t0 + tl;
  const long row = (long)(bidx*TB + t) * (3*DD);
  const int i0 = qq * 8;
  {
    const short8 v1 = *(const short8*)(qkv + row + h*64 + i0);
    const short8 v2 = *(const short8*)(qkv + row + h*64 + 32 + i0);
    short8 o1, o2;
#pragma unroll
    for (int j = 0; j < 8; ++j){
      const float f1 = bf2f((u16)v1[j]), f2 = bf2f((u16)v2[j]);
      const float sv = st[t*32 + i0 + j], cv = ct[t*32 + i0 + j];
      o1[j] = (short)f2bf((f1*cv - f2*sv) * 0.125f);
      o2[j] = (short)f2bf((f2*cv + f1*sv) * 0.125f);
    }
    u16* qp = q_r + ((long)bh*TB + t)*64 + i0;
    *(short8*)qp = o1; *(short8*)(qp + 32) = o2;
  }
  {
    const short8 v1 = *(const short8*)(qkv + row + DD + h*64 + i0);
    const short8 v2 = *(const short8*)(qkv + row + DD + h*64 + 32 + i0);
    short8 o1, o2;
#pragma unroll
    for (int j = 0; j < 8; ++j){
      const float f1 = bf2f((u16)v1[j]), f2 = bf2f((u16)v2[j]);
      const float sv = st[t*32 + i0 + j], cv = ct[t*32 + i0 + j];
      o1[j] = (short)f2bf(f1*cv - f2*sv);
      o2[j] = (short)f2bf(f2*cv + f1*sv);
    }
    u16* kp = k_r + ((long)bh*TB + t)*64 + i0;
    *(short8*)kp = o1; *(short8*)(kp + 32) = o2;
  }
  {
    const short8 w0 = *(const short8*)(qkv + row + 2*DD + h*64 + qq*16);
    const short8 w1 = *(const short8*)(qkv + row + 2*DD + h*64 + qq*16 + 8);
#pragma unroll
    for (int j = 0; j < 8; ++j){
      vt[(qq*16 + j)*72 + tl]     = (u16)w0[j];
      vt[(qq*16 + 8 + j)*72 + tl] = (u16)w1[j];
    }
  }
  __syncthreads();
  {
    const int dh = tid >> 2, seg = tid & 3;
    const short8 r0 = *(const short8*)(vt + dh*72 + seg*16);
    const short8 r1 = *(const short8*)(vt + dh*72 + seg*16 + 8);
    u16* vp = v_t + ((long)bh*64 + dh)*TB + t0 + seg*16;
    *(short8*)vp = r0; *(short8*)(vp + 8) = r1;
  }
}

__global__ __launch_bounds__(256) void k_attn(const u16* __restrict__ q_r,
    const u16* __restrict__ k_r, const u16* __restrict__ v_t, u16* __restrict__ ao)
{
  __shared__ u16 P_lds[4][16*80];
  const int tid = threadIdx.x;
  const int w = tid >> 6, lane = tid & 63;
  const int l15 = lane & 15, l4 = lane >> 4;
  const int bh = blockIdx.y, b = bh >> 4, h = bh & 15;
  const int q0 = blockIdx.x*64 + w*16;
  u16* P = &P_lds[w][0];
  const long qoff = ((long)bh*TB + q0 + l15)*64 + l4*8;
  const short8 Qf0 = *(const short8*)(q_r + qoff);
  const short8 Qf1 = *(const short8*)(q_r + qoff + 32);
  const f32x4 fz = {0.f,0.f,0.f,0.f};
  f32x4 O[4];
  float m[4], L[4];
#pragma unroll
  for (int i = 0; i < 4; ++i){ O[i] = fz; m[i] = -1e30f; L[i] = 0.f; }
  const int ntiles = blockIdx.x + 1;
  for (int stt = 0; stt < ntiles; ++stt){
    const int s0 = stt*64;
    f32x4 S[4];
#pragma unroll
    for (int sj = 0; sj < 4; ++sj){
      const u16* kp = k_r + ((long)bh*TB + s0 + sj*16 + l15)*64 + l4*8;
      const short8 kf0 = *(const short8*)kp;
      const short8 kf1 = *(const short8*)(kp + 32);
      f32x4 z = fz;
      z = __builtin_amdgcn_mfma_f32_16x16x32_bf16(Qf0, kf0, z, 0, 0, 0);
      z = __builtin_amdgcn_mfma_f32_16x16x32_bf16(Qf1, kf1, z, 0, 0, 0);
      S[sj] = z;
    }
    if (stt == blockIdx.x){
#pragma unroll
      for (int sj = 0; sj < 4; ++sj)
#pragma unroll
        for (int r = 0; r < 4; ++r){
          const int sc = s0 + sj*16 + l15;
          const int qr = q0 + l4*4 + r;
          if (sc > qr) S[sj][r] = -1e30f;
        }
    }
    float vm[4];
#pragma unroll
    for (int r = 0; r < 4; ++r){
      vm[r] = fmaxf(fmaxf(S[0][r], S[1][r]), fmaxf(S[2][r], S[3][r]));
      vm[r] = fmaxf(vm[r], __shfl_xor(vm[r], 1));
      vm[r] = fmaxf(vm[r], __shfl_xor(vm[r], 2));
      vm[r] = fmaxf(vm[r], __shfl_xor(vm[r], 4));
      vm[r] = fmaxf(vm[r], __shfl_xor(vm[r], 8));
    }
    float corr[4], ls[4];
#pragma unroll
    for (int r = 0; r < 4; ++r){
      const float mn = fmaxf(m[r], vm[r]);
      corr[r] = __expf(m[r] - mn);
      m[r] = mn;
      ls[r] = 0.f;
    }
#pragma unroll
    for (int sj = 0; sj < 4; ++sj)
#pragma unroll
      for (int r = 0; r < 4; ++r){
        const float pv = __expf(S[sj][r] - m[r]);
        S[sj][r] = pv;
        ls[r] += pv;
      }
#pragma unroll
    for (int r = 0; r < 4; ++r){
      ls[r] += __shfl_xor(ls[r], 1);
      ls[r] += __shfl_xor(ls[r], 2);
      ls[r] += __shfl_xor(ls[r], 4);
      ls[r] += __shfl_xor(ls[r], 8);
      L[r] = L[r]*corr[r] + ls[r];
    }
#pragma unroll
    for (int nj = 0; nj < 4; ++nj)
#pragma unroll
      for (int r = 0; r < 4; ++r)
        O[nj][r] *= corr[r];
#pragma unroll
    for (int sj = 0; sj < 4; ++sj)
#pragma unroll
      for (int r = 0; r < 4; ++r)
        P[(l4*4 + r)*80 + sj*16 + l15] = f2bf(S[sj][r]);
    __syncthreads();
    const short8 pf0 = *(const short8*)(P + l15*80 + l4*8);
    const short8 pf1 = *(const short8*)(P + l15*80 + 32 + l4*8);
#pragma unroll
    for (int nj = 0; nj < 4; ++nj){
      const u16* vp = v_t + ((long)bh*64 + nj*16 + l15)*TB + s0 + l4*8;
      const short8 vf0 = *(const short8*)vp;
      const short8 vf1 = *(const short8*)(vp + 32);
      O[nj] = __builtin_amdgcn_mfma_f32_16x16x32_bf16(pf0, vf0, O[nj], 0, 0, 0);
      O[nj] = __builtin_amdgcn_mfma_f32_16x16x32_bf16(pf1, vf1, O[nj], 0, 0, 0);
    }
    __syncthreads();
  }
#pragma unroll
  for (int nj = 0; nj < 4; ++nj)
#pragma unroll
    for (int r = 0; r < 4; ++r){
      const float val = O[nj][r] / L[r];
      const long orow = (long)b*TB + q0 + l4*4 + r;
      ao[orow*DD + h*64 + nj*16 + l15] = f2bf(val);
    }
}

__global__ __launch_bounds__(256) void k_gemm_proj(const u16* __restrict__ ao,
    const u16* __restrict__ wpT, const float* __restrict__ x, float* __restrict__ out)
{
  GEMM_PRE
  const int id = blockIdx.x;
  const int pcol = id % 8, mt = id / 8;
  const int row0 = mt*128, col0 = pcol*128;
  gemm_core2<false>(ao, DD, nullptr, wpT, DD, DD, 0, row0, col0, As, Bs, acc);
  GEMM_EPI_VARS
#pragma unroll
  for (int mi = 0; mi < 4; ++mi)
#pragma unroll
    for (int ni = 0; ni < 4; ++ni)
#pragma unroll
      for (int r = 0; r < 4; ++r){
        const int rr = row0 + wr*64 + mi*16 + l4*4 + r;
        const int cc = col0 + wc*64 + ni*16 + l15;
        out[(long)rr*DD + cc] = x[(long)rr*DD + cc] + acc[mi][ni][r];
      }
}

__global__ __launch_bounds__(256) void k_router(const float* __restrict__ h2f,
    const float* __restrict__ w_rl, const float* __restrict__ b_rl,
    const float* __restrict__ w_rn, const float* __restrict__ b_rn,
    const float* __restrict__ noise, int2* __restrict__ tok_e, float2* __restrict__ tok_g)
{
  const int tok = blockIdx.x, tid = threadIdx.x;
  const int w = tid >> 6, lane = tid & 63;
  float accl[8] = {0,0,0,0,0,0,0,0};
  float accn[8] = {0,0,0,0,0,0,0,0};
  const float4 hq = *(const float4*)(h2f + (long)tok*DD + tid*4);
  const float hv[4] = {hq.x, hq.y, hq.z, hq.w};
#pragma unroll
  for (int j = 0; j < 4; ++j){
    const int k = tid*4 + j;
    const float4 a = *(const float4*)(w_rl + k*8);
    const float4 b = *(const float4*)(w_rl + k*8 + 4);
    accl[0] += hv[j]*a.x; accl[1] += hv[j]*a.y; accl[2] += hv[j]*a.z; accl[3] += hv[j]*a.w;
    accl[4] += hv[j]*b.x; accl[5] += hv[j]*b.y; accl[6] += hv[j]*b.z; accl[7] += hv[j]*b.w;
    const float4 c = *(const float4*)(w_rn + k*8);
    const float4 d = *(const float4*)(w_rn + k*8 + 4);
    accn[0] += hv[j]*c.x; accn[1] += hv[j]*c.y; accn[2] += hv[j]*c.z; accn[3] += hv[j]*c.w;
    accn[4] += hv[j]*d.x; accn[5] += hv[j]*d.y; accn[6] += hv[j]*d.z; accn[7] += hv[j]*d.w;
  }
  __shared__ float red[4][16];
#pragma unroll
  for (int e = 0; e < 8; ++e){ accl[e] = waveRedSum(accl[e]); accn[e] = waveRedSum(accn[e]); }
  if (lane == 0){
#pragma unroll
    for (int e = 0; e < 8; ++e){ red[w][e] = accl[e]; red[w][8+e] = accn[e]; }
  }
  __syncthreads();
  if (tid == 0){
    float nv[8];
#pragma unroll
    for (int e = 0; e < 8; ++e){
      const float lr = red[0][e]+red[1][e]+red[2][e]+red[3][e] + b_rl[e];
      const float lnv = red[0][8+e]+red[1][8+e]+red[2][8+e]+red[3][8+e] + b_rn[e];
      const float sp = fmaxf(lnv, 0.f) + log1pf(expf(-fabsf(lnv)));
      nv[e] = lr + noise[tok*8 + e] * sp;
    }
    int bi = 0; float bvv = nv[0];
#pragma unroll
    for (int e = 1; e < 8; ++e) if (nv[e] > bvv){ bvv = nv[e]; bi = e; }
    int si = (bi == 0) ? 1 : 0;
    float sv = nv[si];
#pragma unroll
    for (int e = 0; e < 8; ++e) if (e != bi && nv[e] > sv){ sv = nv[e]; si = e; }
    const float tt = expf(sv - bvv);
    tok_e[tok] = make_int2(bi, si);
    tok_g[tok] = make_float2(1.f/(1.f + tt), tt/(1.f + tt));
  }
}

__global__ __launch_bounds__(256) void k_assign(const int2* __restrict__ tok_e,
    int* __restrict__ expert_tok, int* __restrict__ slot_of)
{
  const int e = blockIdx.x, tid = threadIdx.x;
  __shared__ int cnt[256];
  int which[8]; int c = 0;
  const int t0 = tid * 8;
#pragma unroll
  for (int j = 0; j < 8; ++j){
    const int2 te = tok_e[t0 + j];
    int wj = -1;
    if (te.x == e) wj = 0; else if (te.y == e) wj = 1;
    which[j] = wj;
    c += (wj >= 0) ? 1 : 0;
  }
  cnt[tid] = c;
  __syncthreads();
  if (tid == 0){
    int run = 0;
    for (int i = 0; i < 256; ++i){ const int v = cnt[i]; cnt[i] = run; run += v; }
  }
  __syncthreads();
  int pos = cnt[tid];
#pragma unroll
  for (int j = 0; j < 8; ++j){
    if (which[j] >= 0){
      if (pos < CAPN){
        expert_tok[e*CAPN + pos] = t0 + j;
        slot_of[(t0 + j)*2 + which[j]] = e*CAPN + pos;
      }
      ++pos;
    }
  }
}

__global__ __launch_bounds__(256) void k_ffn1(const u16* __restrict__ h2b,
    const u16* __restrict__ w1T, const float* __restrict__ b1,
    const int* __restrict__ expert_tok, u16* __restrict__ act)
{
  GEMM_PRE
  const int z = blockIdx.z;
  const int id = blockIdx.x;
  const int pcol = id % 32, mt = id / 32;
  const int row0 = mt*128, col0 = pcol*128;
  gemm_core2<true>(h2b, DD, expert_tok + z*CAPN, w1T + (long)z*DD*DFF, DD, DD, 0,
                   row0, col0, As, Bs, acc);
  GEMM_EPI_VARS
#pragma unroll
  for (int mi = 0; mi < 4; ++mi)
#pragma unroll
    for (int ni = 0; ni < 4; ++ni)
#pragma unroll
      for (int r = 0; r < 4; ++r){
        const int rr = row0 + wr*64 + mi*16 + l4*4 + r;
        const int cc = col0 + wc*64 + ni*16 + l15;
        const float val = fmaxf(acc[mi][ni][r] + b1[z*DFF + cc], 0.f);
        act[((long)z*CAPN + rr)*DFF + cc] = f2bf(val);
      }
}

// split-K=2: blockIdx.x = pcol(8) x mt(4) x ks(2); K=2048 each
__global__ __launch_bounds__(256) void k_ffn2(const u16* __restrict__ act,
    const u16* __restrict__ w2T, float* __restrict__ partial)
{
  GEMM_PRE
  const int z = blockIdx.z;
  const int id = blockIdx.x;
  const int pcol = id & 7, mt = (id >> 3) & 3, ks = id >> 5;
  const int row0 = mt*128, col0 = pcol*128;
  gemm_core2<false>(act + (long)z*CAPN*DFF, DFF, nullptr,
                    w2T + (long)z*DFF*DD, DFF, 2048, ks*2048,
                    row0, col0, As, Bs, acc);
  GEMM_EPI_VARS
  float* pp = partial + (long)ks*NEXPERT*CAPN*DD;
#pragma unroll
  for (int mi = 0; mi < 4; ++mi)
#pragma unroll
    for (int ni = 0; ni < 4; ++ni)
#pragma unroll
      for (int r = 0; r < 4; ++r){
        const int rr = row0 + wr*64 + mi*16 + l4*4 + r;
        const int cc = col0 + wc*64 + ni*16 + l15;
        pp[((long)z*CAPN + rr)*DD + cc] = acc[mi][ni][r];
      }
}

__global__ __launch_bounds__(256) void k_ffn2red(const float* __restrict__ partial,
    const float* __restrict__ b2, float* __restrict__ out_e)
{
  const long i = ((long)blockIdx.x*256 + threadIdx.x)*4;
  const float4 p0 = *(const float4*)(partial + i);
  const float4 p1 = *(const float4*)(partial + (long)NEXPERT*CAPN*DD + i);
  const int col = (int)(i & (DD-1));
  const int e = (int)(i >> 19);
  const float4 bv = *(const float4*)(b2 + e*DD + col);
  float4 o;
  o.x = p0.x + p1.x + bv.x;
  o.y = p0.y + p1.y + bv.y;
  o.z = p0.z + p1.z + bv.z;
  o.w = p0.w + p1.w + bv.w;
  *(float4*)(out_e + i) = o;
}

__global__ __launch_bounds__(256) void k_combine(float* __restrict__ out,
    const int* __restrict__ slot_of, const float2* __restrict__ tok_g,
    const float* __restrict__ out_e)
{
  const int tok = blockIdx.x, c = threadIdx.x * 4;
  float4 o = *(float4*)(out + (long)tok*DD + c);
  const int s0 = slot_of[tok*2], s1 = slot_of[tok*2 + 1];
  const float2 g = tok_g[tok];
  if (s0 >= 0){
    const float4 v = *(const float4*)(out_e + (long)s0*DD + c);
    o.x += g.x*v.x; o.y += g.x*v.y; o.z += g.x*v.z; o.w += g.x*v.w;
  }
  if (s1 >= 0){
    const float4 v = *(const float4*)(out_e + (long)s1*DD + c);
    o.x += g.y*v.x; o.y += g.y*v.y; o.z += g.y*v.z; o.w += g.y*v.w;
  }
  *(float4*)(out + (long)tok*DD + c) = o;
}

// ---------------------------------------------------------------- launcher
extern "C" void kernel_launch(void* const* d_in, const int* in_sizes, int n_in,
                              void* d_out, int out_size, void* d_ws, size_t ws_size,
                              hipStream_t stream)
{
  (void)in_sizes; (void)n_in; (void)out_size; (void)ws_size;
  const float* x      = (const float*)d_in[0];
  const float* noise  = (const float*)d_in[1];
  const float* ln1_g  = (const float*)d_in[2];
  const float* ln1_b  = (const float*)d_in[3];
  const float* ln2_g  = (const float*)d_in[4];
  const float* ln2_b  = (const float*)d_in[5];
  const float* w_qkv  = (const float*)d_in[6];
  const float* w_proj = (const float*)d_in[7];
  const float* w_rl   = (const float*)d_in[8];
  const float* b_rl   = (const float*)d_in[9];
  const float* w_rn   = (const float*)d_in[10];
  const float* b_rn   = (const float*)d_in[11];
  const float* w1     = (const float*)d_in[12];
  const float* b1     = (const float*)d_in[13];
  const float* w2     = (const float*)d_in[14];
  const float* b2     = (const float*)d_in[15];
  float* out = (float*)d_out;

  char* p = (char*)d_ws;
  auto carve = [&](size_t bytes) -> void* {
    void* r = (void*)p;
    p += (bytes + 255) & ~(size_t)255;
    return r;
  };
  float* sin_t      = (float*)carve((size_t)TB*32*4);
  float* cos_t      = (float*)carve((size_t)TB*32*4);
  // attention-phase region (reused as `act` in MoE phase)
  char*  region     = (char*)carve((size_t)NTOK*DD*2*8); // 32MB
  u16*   h1  = (u16*)region;
  u16*   qkv = (u16*)(region + (size_t)NTOK*DD*2);
  u16*   q_r = (u16*)(region + (size_t)NTOK*DD*2*4);
  u16*   k_r = (u16*)(region + (size_t)NTOK*DD*2*5);
  u16*   v_t = (u16*)(region + (size_t)NTOK*DD*2*6);
  u16*   ao  = (u16*)(region + (size_t)NTOK*DD*2*7);
  u16*   act = (u16*)region; // 8*512*4096*2 = 32MB, aliases attn buffers
  u16*   h2b        = (u16*)  carve((size_t)NTOK*DD*2);
  float* h2f        = (float*)carve((size_t)NTOK*DD*4);
  int2*  tok_e      = (int2*) carve((size_t)NTOK*8);
  float2* tok_g     = (float2*)carve((size_t)NTOK*8);
  int*   slot_of    = (int*)  carve((size_t)NTOK*2*4);
  int*   expert_tok = (int*)  carve((size_t)NEXPERT*CAPN*4);
  u16*   wqkvT      = (u16*)  carve((size_t)DD*3*DD*2);
  u16*   wprojT     = (u16*)  carve((size_t)DD*DD*2);
  u16*   w1T        = (u16*)  carve((size_t)NEXPERT*DD*DFF*2);
  u16*   w2T        = (u16*)  carve((size_t)NEXPERT*DFF*DD*2);
  float* out_e      = (float*)carve((size_t)NEXPERT*CAPN*DD*4);
  float* partial    = (float*)carve((size_t)2*NEXPERT*CAPN*DD*4);

  k_init   <<<16, 256, 0, stream>>>(expert_tok, slot_of);
  k_sincos <<<128, 256, 0, stream>>>(sin_t, cos_t);
  k_wt     <<<dim3(48, 16, 1), 256, 0, stream>>>(w_qkv, wqkvT, DD, 3*DD);
  k_wt     <<<dim3(16, 16, 1), 256, 0, stream>>>(w_proj, wprojT, DD, DD);
  k_wt     <<<dim3(64, 16, NEXPERT), 256, 0, stream>>>(w1, w1T, DD, DFF);
  k_wt     <<<dim3(16, 64, NEXPERT), 256, 0, stream>>>(w2, w2T, DFF, DD);
  k_ln     <<<NTOK, 256, 0, stream>>>(x, ln1_g, ln1_b, h1, nullptr);
  k_gemm_qkv<<<384, 256, 0, stream>>>(h1, wqkvT, qkv);
  k_rope   <<<dim3(16, 32), 256, 0, stream>>>(qkv, sin_t, cos_t, q_r, k_r, v_t);
  k_attn   <<<dim3(16, 32), 256, 0, stream>>>(q_r, k_r, v_t, ao);
  k_gemm_proj<<<128, 256, 0, stream>>>(ao, wprojT, x, out);
  k_ln     <<<NTOK, 256, 0, stream>>>(out, ln2_g, ln2_b, h2b, h2f);
  k_router <<<NTOK, 256, 0, stream>>>(h2f, w_rl, b_rl, w_rn, b_rn, noise, tok_e, tok_g);
  k_assign <<<NEXPERT, 256, 0, stream>>>(tok_e, expert_tok, slot_of);
  k_ffn1   <<<dim3(128, 1, NEXPERT), 256, 0, stream>>>(h2b, w1T, b1, expert_tok, act);
  k_ffn2   <<<dim3(64, 1, NEXPERT), 256, 0, stream>>>(act, w2T, partial);
  k_ffn2red<<<16384, 256, 0, stream>>>(partial, b2, out_e);
  k_combine<<<NTOK, 256, 0, stream>>>(out, slot_of, tok_g, out_e);
}

// Round 3
// 406.487 us; speedup vs baseline: 1.1626x; 1.1029x over previous
//
#include <hip/hip_runtime.h>

// MoE transformer block: LN1 -> QKV -> RoPE -> split-KV causal flash attn ->
// proj+res -> LN2 -> noisy top-2 router (cap 512) -> expert FFN (split-K=4,
// partials reduced in combine) -> combine.
// GEMMs: bf16 MFMA 16x16x32, 128^2 tile, BK=64, global_load_lds dwordx4.

#define TB 1024   // T
#define DD 1024   // D
#define NTOK 2048 // B*T
#define NEXPERT 8
#define CAPN 512
#define DFF 4096

typedef __attribute__((ext_vector_type(4))) float f32x4;
typedef __attribute__((ext_vector_type(8))) short short8;
typedef __attribute__((ext_vector_type(4))) short short4v;
typedef unsigned short u16;
typedef unsigned int u32;

__device__ __forceinline__ u16 f2bf(float f){
  union { float f; u32 u; } v; v.f = f;
  u32 u = v.u;
  u32 r = (u + 0x7fffu + ((u >> 16) & 1u)) >> 16;
  return (u16)r;
}
__device__ __forceinline__ float bf2f(u16 b){
  union { u32 u; float f; } v; v.u = ((u32)b) << 16;
  return v.f;
}
__device__ __forceinline__ float waveRedSum(float v){
#pragma unroll
  for (int o = 1; o < 64; o <<= 1) v += __shfl_xor(v, o);
  return v;
}

// async global->LDS, 16B per lane, wave-uniform LDS base + lane*16
__device__ __forceinline__ void gl16(const u16* g, u16* l){
  __builtin_amdgcn_global_load_lds(
    (const __attribute__((address_space(1))) u32*)g,
    (__attribute__((address_space(3))) u32*)l, 16, 0, 0);
}

// ------------------------------------------------------------- weight prep
// src fp32 [K][N] -> dst bf16 [N][K]; 64x64 tiles; blockIdx.z = expert.
__global__ __launch_bounds__(256) void k_wt(const float* __restrict__ src,
    u16* __restrict__ dst, int K, int N)
{
  __shared__ float tile[64][65];
  const long zoff = (long)blockIdx.z * K * N;
  const int k0 = blockIdx.y * 64, n0 = blockIdx.x * 64;
  const int tid = threadIdx.x;
  const int r  = tid >> 2;
  const int c4 = (tid & 3) * 16;
#pragma unroll
  for (int j = 0; j < 4; ++j){
    const float4 v = *(const float4*)(src + zoff + (long)(k0 + r)*N + n0 + c4 + j*4);
    tile[r][c4 + j*4 + 0] = v.x;
    tile[r][c4 + j*4 + 1] = v.y;
    tile[r][c4 + j*4 + 2] = v.z;
    tile[r][c4 + j*4 + 3] = v.w;
  }
  __syncthreads();
  const int n  = tid >> 2;
  const int ks = (tid & 3) * 16;
  short8 o0, o1;
#pragma unroll
  for (int j = 0; j < 8; ++j){
    o0[j] = (short)f2bf(tile[ks + j][n]);
    o1[j] = (short)f2bf(tile[ks + 8 + j][n]);
  }
  u16* dp = dst + zoff + (long)(n0 + n)*K + k0 + ks;
  *(short8*)dp = o0;
  *(short8*)(dp + 8) = o1;
}

// ---------------------------------------------------------------- GEMM core
// C 128x128 tile, 4 waves 2x2, A bf16 [M,K] (opt row-gather), B bf16 [N,K].
// BK=64: per k-step each wave issues 8 gl16 (4 A-chunks + 4 B-chunks of
// 8 rows x 128B), then 16 ds_read_b128 + 32 MFMA between 2 barriers.
template<bool GATHER>
__device__ __forceinline__ void gemm_core3(
    const u16* __restrict__ A, int lda, const int* __restrict__ rowlist,
    const u16* __restrict__ Bt, int ldb, int K, int kstart, int row0, int col0,
    u16* As, u16* Bs, f32x4 acc[4][4])
{
  const int tid = threadIdx.x;
  const int lane = tid & 63;
  const int w = tid >> 6;
  const int wr = w >> 1, wc = w & 1;
  const int l15 = lane & 15, l4 = lane >> 4;
  const int rr8 = lane >> 3;        // 0..7 row within 8-row chunk
  const int cc8 = (lane & 7) * 8;   // u16 col within 128B row

  const u16* Aq[4];
  const u16* Bq[4];
  u16* AsD[4];
  u16* BsD[4];
#pragma unroll
  for (int j2 = 0; j2 < 4; ++j2){
    const int j = w + 4*j2;         // chunk 0..15
    long ar;
    if constexpr (GATHER) ar = rowlist[row0 + j*8 + rr8];
    else                  ar = row0 + j*8 + rr8;
    Aq[j2] = A + ar*(long)lda + kstart + cc8;
    Bq[j2] = Bt + (long)(col0 + j*8 + rr8)*ldb + kstart + cc8;
    AsD[j2] = As + j*512;           // 8 rows * 64 u16
    BsD[j2] = Bs + j*512;
  }

  for (int k0 = 0; k0 < K; k0 += 64){
#pragma unroll
    for (int j2 = 0; j2 < 4; ++j2){
      gl16(Aq[j2] + k0, AsD[j2]);
      gl16(Bq[j2] + k0, BsD[j2]);
    }
    __syncthreads();
    short8 aF[2][4], bF[2][4];
#pragma unroll
    for (int kk = 0; kk < 2; ++kk){
#pragma unroll
      for (int mi = 0; mi < 4; ++mi)
        aF[kk][mi] = *(const short8*)(As + (wr*64 + mi*16 + l15)*64 + kk*32 + l4*8);
#pragma unroll
      for (int ni = 0; ni < 4; ++ni)
        bF[kk][ni] = *(const short8*)(Bs + (wc*64 + ni*16 + l15)*64 + kk*32 + l4*8);
    }
#pragma unroll
    for (int kk = 0; kk < 2; ++kk)
#pragma unroll
      for (int mi = 0; mi < 4; ++mi)
#pragma unroll
        for (int ni = 0; ni < 4; ++ni)
          acc[mi][ni] = __builtin_amdgcn_mfma_f32_16x16x32_bf16(aF[kk][mi], bF[kk][ni], acc[mi][ni], 0, 0, 0);
    __syncthreads();
  }
}

#define GEMM_PRE \
  __shared__ u16 As[128*64], Bs[128*64]; \
  const f32x4 fz = {0.f,0.f,0.f,0.f}; \
  f32x4 acc[4][4]; \
  _Pragma("unroll") for (int i = 0; i < 4; ++i) \
  _Pragma("unroll") for (int j = 0; j < 4; ++j) acc[i][j] = fz;

#define GEMM_EPI_VARS \
  const int lane = threadIdx.x & 63; \
  const int wv = threadIdx.x >> 6;   \
  const int wr = wv >> 1, wc = wv & 1; \
  const int l15 = lane & 15, l4 = lane >> 4;

// ---------------------------------------------------------------- kernels
__global__ __launch_bounds__(256) void k_init(int* expert_tok, int* slot_of){
  const int i = blockIdx.x * 256 + threadIdx.x;
  expert_tok[i] = 0;
  slot_of[i] = -1;
}

__global__ __launch_bounds__(256) void k_sincos(float* __restrict__ st, float* __restrict__ ct){
  const int idx = blockIdx.x * 256 + threadIdx.x;
  const int t = idx >> 5, i = idx & 31;
  const float inv = expf((float)(2 * i) * (-0.14391157f));
  const float ang = (float)t * inv;
  st[idx] = sinf(ang);
  ct[idx] = cosf(ang);
}

__global__ __launch_bounds__(256) void k_ln(const float* __restrict__ x,
    const float* __restrict__ g, const float* __restrict__ bb,
    u16* __restrict__ hb, float* __restrict__ hf)
{
  const int row = blockIdx.x, tid = threadIdx.x;
  const int w = tid >> 6, lane = tid & 63;
  const float4 xv = *(const float4*)(x + (long)row*DD + tid*4);
  __shared__ float red[8];
  float s = xv.x + xv.y + xv.z + xv.w;
  s = waveRedSum(s);
  if (lane == 0) red[w] = s;
  __syncthreads();
  const float mean = (red[0]+red[1]+red[2]+red[3]) * (1.f/1024.f);
  const float d0 = xv.x-mean, d1 = xv.y-mean, d2 = xv.z-mean, d3 = xv.w-mean;
  float vs = d0*d0 + d1*d1 + d2*d2 + d3*d3;
  vs = waveRedSum(vs);
  if (lane == 0) red[4+w] = vs;
  __syncthreads();
  const float var = (red[4]+red[5]+red[6]+red[7]) * (1.f/1024.f);
  const float inv = rsqrtf(var + 1e-5f);
  const int c = tid*4;
  const float y0 = d0*inv*g[c+0] + bb[c+0];
  const float y1 = d1*inv*g[c+1] + bb[c+1];
  const float y2 = d2*inv*g[c+2] + bb[c+2];
  const float y3 = d3*inv*g[c+3] + bb[c+3];
  short4v p;
  p[0] = (short)f2bf(y0); p[1] = (short)f2bf(y1);
  p[2] = (short)f2bf(y2); p[3] = (short)f2bf(y3);
  *(short4v*)(hb + (long)row*DD + c) = p;
  if (hf){
    float4 o; o.x = y0; o.y = y1; o.z = y2; o.w = y3;
    *(float4*)(hf + (long)row*DD + c) = o;
  }
}

__global__ __launch_bounds__(256) void k_gemm_qkv(const u16* __restrict__ h1,
    const u16* __restrict__ wqT, u16* __restrict__ qkv)
{
  GEMM_PRE
  const int id = blockIdx.x;
  const int pcol = id % 24, mt = id / 24;
  const int row0 = mt*128, col0 = pcol*128;
  gemm_core3<false>(h1, DD, nullptr, wqT, DD, DD, 0, row0, col0, As, Bs, acc);
  GEMM_EPI_VARS
#pragma unroll
  for (int mi = 0; mi < 4; ++mi)
#pragma unroll
    for (int ni = 0; ni < 4; ++ni)
#pragma unroll
      for (int r = 0; r < 4; ++r){
        const int rr = row0 + wr*64 + mi*16 + l4*4 + r;
        const int cc = col0 + wc*64 + ni*16 + l15;
        qkv[(long)rr*(3*DD) + cc] = f2bf(acc[mi][ni][r]);
      }
}

__global__ __launch_bounds__(256) void k_rope(const u16* __restrict__ qkv,
    const float* __restrict__ st, const float* __restrict__ ct,
    u16* __restrict__ q_r, u16* __restrict__ k_r, u16* __restrict__ v_t)
{
  __shared__ u16 vt[64*72];
  const int tid = threadIdx.x;
  const int bh = blockIdx.y, bidx = bh >> 4, h = bh & 15;
  const int t0 = blockIdx.x * 64;
  const int tl = tid >> 2, qq = tid & 3;
  const int t = t0 + tl;
  const long row = (long)(bidx*TB + t) * (3*DD);
  const int i0 = qq * 8;
  {
    const short8 v1 = *(const short8*)(qkv + row + h*64 + i0);
    const short8 v2 = *(const short8*)(qkv + row + h*64 + 32 + i0);
    short8 o1, o2;
#pragma unroll
    for (int j = 0; j < 8; ++j){
      const float f1 = bf2f((u16)v1[j]), f2 = bf2f((u16)v2[j]);
      const float sv = st[t*32 + i0 + j], cv = ct[t*32 + i0 + j];
      o1[j] = (short)f2bf((f1*cv - f2*sv) * 0.125f);
      o2[j] = (short)f2bf((f2*cv + f1*sv) * 0.125f);
    }
    u16* qp = q_r + ((long)bh*TB + t)*64 + i0;
    *(short8*)qp = o1; *(short8*)(qp + 32) = o2;
  }
  {
    const short8 v1 = *(const short8*)(qkv + row + DD + h*64 + i0);
    const short8 v2 = *(const short8*)(qkv + row + DD + h*64 + 32 + i0);
    short8 o1, o2;
#pragma unroll
    for (int j = 0; j < 8; ++j){
      const float f1 = bf2f((u16)v1[j]), f2 = bf2f((u16)v2[j]);
      const float sv = st[t*32 + i0 + j], cv = ct[t*32 + i0 + j];
      o1[j] = (short)f2bf(f1*cv - f2*sv);
      o2[j] = (short)f2bf(f2*cv + f1*sv);
    }
    u16* kp = k_r + ((long)bh*TB + t)*64 + i0;
    *(short8*)kp = o1; *(short8*)(kp + 32) = o2;
  }
  {
    const short8 w0 = *(const short8*)(qkv + row + 2*DD + h*64 + qq*16);
    const short8 w1 = *(const short8*)(qkv + row + 2*DD + h*64 + qq*16 + 8);
#pragma unroll
    for (int j = 0; j < 8; ++j){
      vt[(qq*16 + j)*72 + tl]     = (u16)w0[j];
      vt[(qq*16 + 8 + j)*72 + tl] = (u16)w1[j];
    }
  }
  __syncthreads();
  {
    const int dh = tid >> 2, seg = tid & 3;
    const short8 r0 = *(const short8*)(vt + dh*72 + seg*16);
    const short8 r1 = *(const short8*)(vt + dh*72 + seg*16 + 8);
    u16* vp = v_t + ((long)bh*64 + dh)*TB + t0 + seg*16;
    *(short8*)vp = r0; *(short8*)(vp + 8) = r1;
  }
}

// split-KV flash attention: grid (qtile 8, bh 32, chunk 2), 8 waves/block,
// wave = 16 q rows. Chunks of 512 kv. Writes unnormalized O (bf16) + (m,L).
// P staging is wave-private -> no cross-wave barriers (lgkmcnt only).
__global__ __launch_bounds__(512) void k_attn(const u16* __restrict__ q_r,
    const u16* __restrict__ k_r, const u16* __restrict__ v_t,
    u16* __restrict__ aoc, float2* __restrict__ mLc)
{
  const int qt = blockIdx.x, bh = blockIdx.y, ch = blockIdx.z;
  const int kvlen = (qt + 1) * 128;
  const int s_begin = ch * 512;
  if (s_begin >= kvlen) return;
  const int ntile = (min(s_begin + 512, kvlen) - s_begin) >> 6;

  __shared__ u16 P_lds[8][16*80];
  const int tid = threadIdx.x;
  const int w = tid >> 6, lane = tid & 63;
  const int l15 = lane & 15, l4 = lane >> 4;
  const int q0 = qt*128 + w*16;
  u16* P = &P_lds[w][0];
  const long qoff = ((long)bh*TB + q0 + l15)*64 + l4*8;
  const short8 Qf0 = *(const short8*)(q_r + qoff);
  const short8 Qf1 = *(const short8*)(q_r + qoff + 32);
  const f32x4 fz = {0.f,0.f,0.f,0.f};
  f32x4 O[4];
  float m[4], L[4];
#pragma unroll
  for (int i = 0; i < 4; ++i){ O[i] = fz; m[i] = -1e30f; L[i] = 0.f; }

  for (int t = 0; t < ntile; ++t){
    const int s0 = s_begin + t*64;
    if (s0 > q0 + 15) continue;          // tile fully above diagonal (wave-uniform)
    f32x4 S[4];
#pragma unroll
    for (int sj = 0; sj < 4; ++sj){
      const u16* kp = k_r + ((long)bh*TB + s0 + sj*16 + l15)*64 + l4*8;
      const short8 kf0 = *(const short8*)kp;
      const short8 kf1 = *(const short8*)(kp + 32);
      f32x4 z = fz;
      z = __builtin_amdgcn_mfma_f32_16x16x32_bf16(Qf0, kf0, z, 0, 0, 0);
      z = __builtin_amdgcn_mfma_f32_16x16x32_bf16(Qf1, kf1, z, 0, 0, 0);
      S[sj] = z;
    }
    if (s0 + 63 > q0){                   // tile touches diagonal: mask
#pragma unroll
      for (int sj = 0; sj < 4; ++sj)
#pragma unroll
        for (int r = 0; r < 4; ++r){
          const int sc = s0 + sj*16 + l15;
          const int qr = q0 + l4*4 + r;
          if (sc > qr) S[sj][r] = -1e30f;
        }
    }
    float vm[4];
#pragma unroll
    for (int r = 0; r < 4; ++r){
      vm[r] = fmaxf(fmaxf(S[0][r], S[1][r]), fmaxf(S[2][r], S[3][r]));
      vm[r] = fmaxf(vm[r], __shfl_xor(vm[r], 1));
      vm[r] = fmaxf(vm[r], __shfl_xor(vm[r], 2));
      vm[r] = fmaxf(vm[r], __shfl_xor(vm[r], 4));
      vm[r] = fmaxf(vm[r], __shfl_xor(vm[r], 8));
    }
    float corr[4], ls[4];
#pragma unroll
    for (int r = 0; r < 4; ++r){
      const float mn = fmaxf(m[r], vm[r]);
      corr[r] = __expf(m[r] - mn);
      m[r] = mn;
      ls[r] = 0.f;
    }
#pragma unroll
    for (int sj = 0; sj < 4; ++sj)
#pragma unroll
      for (int r = 0; r < 4; ++r){
        const float pv = __expf(S[sj][r] - m[r]);
        S[sj][r] = pv;
        ls[r] += pv;
      }
#pragma unroll
    for (int r = 0; r < 4; ++r){
      ls[r] += __shfl_xor(ls[r], 1);
      ls[r] += __shfl_xor(ls[r], 2);
      ls[r] += __shfl_xor(ls[r], 4);
      ls[r] += __shfl_xor(ls[r], 8);
      L[r] = L[r]*corr[r] + ls[r];
    }
#pragma unroll
    for (int nj = 0; nj < 4; ++nj)
#pragma unroll
      for (int r = 0; r < 4; ++r)
        O[nj][r] *= corr[r];
#pragma unroll
    for (int sj = 0; sj < 4; ++sj)
#pragma unroll
      for (int r = 0; r < 4; ++r)
        P[(l4*4 + r)*80 + sj*16 + l15] = f2bf(S[sj][r]);
    asm volatile("s_waitcnt lgkmcnt(0)" ::: "memory");
    __builtin_amdgcn_sched_barrier(0);
    const short8 pf0 = *(const short8*)(P + l15*80 + l4*8);
    const short8 pf1 = *(const short8*)(P + l15*80 + 32 + l4*8);
#pragma unroll
    for (int nj = 0; nj < 4; ++nj){
      const u16* vp = v_t + ((long)bh*64 + nj*16 + l15)*TB + s0 + l4*8;
      const short8 vf0 = *(const short8*)vp;
      const short8 vf1 = *(const short8*)(vp + 32);
      O[nj] = __builtin_amdgcn_mfma_f32_16x16x32_bf16(pf0, vf0, O[nj], 0, 0, 0);
      O[nj] = __builtin_amdgcn_mfma_f32_16x16x32_bf16(pf1, vf1, O[nj], 0, 0, 0);
    }
  }
  const long obase = ((long)(bh*8 + qt)*2 + ch) * 8192;
#pragma unroll
  for (int nj = 0; nj < 4; ++nj)
#pragma unroll
    for (int r = 0; r < 4; ++r)
      aoc[obase + (long)(w*16 + l4*4 + r)*64 + nj*16 + l15] = f2bf(O[nj][r]);
  if (l15 == 0){
#pragma unroll
    for (int r = 0; r < 4; ++r)
      mLc[((long)(bh*8 + qt)*2 + ch)*128 + w*16 + l4*4 + r] = make_float2(m[r], L[r]);
  }
}

// merge attention chunks -> ao bf16 [B*T][D]
__global__ __launch_bounds__(256) void k_attn_comb(const u16* __restrict__ aoc,
    const float2* __restrict__ mLc, u16* __restrict__ ao)
{
  const int bq = blockIdx.x;              // bh*8 + qt
  const int qt = bq & 7, bh = bq >> 3, b = bh >> 4, h = bh & 15;
  const int nc2 = (qt >= 4);
  const int d = threadIdx.x & 63;
  const int r0 = threadIdx.x >> 6;
  const long base = (long)bq * 2 * 8192;
  const long mbase = (long)bq * 2 * 128;
  for (int rp = 0; rp < 32; ++rp){
    const int r = rp*4 + r0;
    const float2 ml0 = mLc[mbase + r];
    float o, Lg;
    if (nc2){
      const float2 ml1 = mLc[mbase + 128 + r];
      const float mg = fmaxf(ml0.x, ml1.x);
      const float w0 = __expf(ml0.x - mg), w1 = __expf(ml1.x - mg);
      o  = w0 * bf2f(aoc[base + (long)r*64 + d]) + w1 * bf2f(aoc[base + 8192 + (long)r*64 + d]);
      Lg = w0 * ml0.y + w1 * ml1.y;
    } else {
      o  = bf2f(aoc[base + (long)r*64 + d]);
      Lg = ml0.y;
    }
    const int t = qt*128 + r;
    ao[((long)b*TB + t)*DD + h*64 + d] = f2bf(o / Lg);
  }
}

__global__ __launch_bounds__(256) void k_gemm_proj(const u16* __restrict__ ao,
    const u16* __restrict__ wpT, const float* __restrict__ x, float* __restrict__ out)
{
  GEMM_PRE
  const int id = blockIdx.x;
  const int pcol = id % 8, mt = id / 8;
  const int row0 = mt*128, col0 = pcol*128;
  gemm_core3<false>(ao, DD, nullptr, wpT, DD, DD, 0, row0, col0, As, Bs, acc);
  GEMM_EPI_VARS
#pragma unroll
  for (int mi = 0; mi < 4; ++mi)
#pragma unroll
    for (int ni = 0; ni < 4; ++ni)
#pragma unroll
      for (int r = 0; r < 4; ++r){
        const int rr = row0 + wr*64 + mi*16 + l4*4 + r;
        const int cc = col0 + wc*64 + ni*16 + l15;
        out[(long)rr*DD + cc] = x[(long)rr*DD + cc] + acc[mi][ni][r];
      }
}

__global__ __launch_bounds__(256) void k_router(const float* __restrict__ h2f,
    const float* __restrict__ w_rl, const float* __restrict__ b_rl,
    const float* __restrict__ w_rn, const float* __restrict__ b_rn,
    const float* __restrict__ noise, int2* __restrict__ tok_e, float2* __restrict__ tok_g)
{
  const int tok = blockIdx.x, tid = threadIdx.x;
  const int w = tid >> 6, lane = tid & 63;
  float accl[8] = {0,0,0,0,0,0,0,0};
  float accn[8] = {0,0,0,0,0,0,0,0};
  const float4 hq = *(const float4*)(h2f + (long)tok*DD + tid*4);
  const float hv[4] = {hq.x, hq.y, hq.z, hq.w};
#pragma unroll
  for (int j = 0; j < 4; ++j){
    const int k = tid*4 + j;
    const float4 a = *(const float4*)(w_rl + k*8);
    const float4 b = *(const float4*)(w_rl + k*8 + 4);
    accl[0] += hv[j]*a.x; accl[1] += hv[j]*a.y; accl[2] += hv[j]*a.z; accl[3] += hv[j]*a.w;
    accl[4] += hv[j]*b.x; accl[5] += hv[j]*b.y; accl[6] += hv[j]*b.z; accl[7] += hv[j]*b.w;
    const float4 c = *(const float4*)(w_rn + k*8);
    const float4 d = *(const float4*)(w_rn + k*8 + 4);
    accn[0] += hv[j]*c.x; accn[1] += hv[j]*c.y; accn[2] += hv[j]*c.z; accn[3] += hv[j]*c.w;
    accn[4] += hv[j]*d.x; accn[5] += hv[j]*d.y; accn[6] += hv[j]*d.z; accn[7] += hv[j]*d.w;
  }
  __shared__ float red[4][16];
#pragma unroll
  for (int e = 0; e < 8; ++e){ accl[e] = waveRedSum(accl[e]); accn[e] = waveRedSum(accn[e]); }
  if (lane == 0){
#pragma unroll
    for (int e = 0; e < 8; ++e){ red[w][e] = accl[e]; red[w][8+e] = accn[e]; }
  }
  __syncthreads();
  if (tid == 0){
    float nv[8];
#pragma unroll
    for (int e = 0; e < 8; ++e){
      const float lr = red[0][e]+red[1][e]+red[2][e]+red[3][e] + b_rl[e];
      const float lnv = red[0][8+e]+red[1][8+e]+red[2][8+e]+red[3][8+e] + b_rn[e];
      const float sp = fmaxf(lnv, 0.f) + log1pf(expf(-fabsf(lnv)));
      nv[e] = lr + noise[tok*8 + e] * sp;
    }
    int bi = 0; float bvv = nv[0];
#pragma unroll
    for (int e = 1; e < 8; ++e) if (nv[e] > bvv){ bvv = nv[e]; bi = e; }
    int si = (bi == 0) ? 1 : 0;
    float sv = nv[si];
#pragma unroll
    for (int e = 0; e < 8; ++e) if (e != bi && nv[e] > sv){ sv = nv[e]; si = e; }
    const float tt = expf(sv - bvv);
    tok_e[tok] = make_int2(bi, si);
    tok_g[tok] = make_float2(1.f/(1.f + tt), tt/(1.f + tt));
  }
}

__global__ __launch_bounds__(256) void k_assign(const int2* __restrict__ tok_e,
    int* __restrict__ expert_tok, int* __restrict__ slot_of)
{
  const int e = blockIdx.x, tid = threadIdx.x;
  __shared__ int cnt[256];
  int which[8]; int c = 0;
  const int t0 = tid * 8;
#pragma unroll
  for (int j = 0; j < 8; ++j){
    const int2 te = tok_e[t0 + j];
    int wj = -1;
    if (te.x == e) wj = 0; else if (te.y == e) wj = 1;
    which[j] = wj;
    c += (wj >= 0) ? 1 : 0;
  }
  cnt[tid] = c;
  __syncthreads();
  if (tid == 0){
    int run = 0;
    for (int i = 0; i < 256; ++i){ const int v = cnt[i]; cnt[i] = run; run += v; }
  }
  __syncthreads();
  int pos = cnt[tid];
#pragma unroll
  for (int j = 0; j < 8; ++j){
    if (which[j] >= 0){
      if (pos < CAPN){
        expert_tok[e*CAPN + pos] = t0 + j;
        slot_of[(t0 + j)*2 + which[j]] = e*CAPN + pos;
      }
      ++pos;
    }
  }
}

__global__ __launch_bounds__(256) void k_ffn1(const u16* __restrict__ h2b,
    const u16* __restrict__ w1T, const float* __restrict__ b1,
    const int* __restrict__ expert_tok, u16* __restrict__ act)
{
  GEMM_PRE
  const int z = blockIdx.z;
  const int id = blockIdx.x;
  const int pcol = id % 32, mt = id / 32;
  const int row0 = mt*128, col0 = pcol*128;
  gemm_core3<true>(h2b, DD, expert_tok + z*CAPN, w1T + (long)z*DD*DFF, DD, DD, 0,
                   row0, col0, As, Bs, acc);
  GEMM_EPI_VARS
#pragma unroll
  for (int mi = 0; mi < 4; ++mi)
#pragma unroll
    for (int ni = 0; ni < 4; ++ni)
#pragma unroll
      for (int r = 0; r < 4; ++r){
        const int rr = row0 + wr*64 + mi*16 + l4*4 + r;
        const int cc = col0 + wc*64 + ni*16 + l15;
        const float val = fmaxf(acc[mi][ni][r] + b1[z*DFF + cc], 0.f);
        act[((long)z*CAPN + rr)*DFF + cc] = f2bf(val);
      }
}

// split-K=4: blockIdx.x = pcol(8) x mt(4) x ks(4); K=1024 each
__global__ __launch_bounds__(256) void k_ffn2(const u16* __restrict__ act,
    const u16* __restrict__ w2T, float* __restrict__ partial)
{
  GEMM_PRE
  const int z = blockIdx.z;
  const int id = blockIdx.x;
  const int pcol = id & 7, mt = (id >> 3) & 3, ks = id >> 5;
  const int row0 = mt*128, col0 = pcol*128;
  gemm_core3<false>(act + (long)z*CAPN*DFF, DFF, nullptr,
                    w2T + (long)z*DFF*DD, DFF, 1024, ks*1024,
                    row0, col0, As, Bs, acc);
  GEMM_EPI_VARS
  float* pp = partial + (long)ks*NEXPERT*CAPN*DD;
#pragma unroll
  for (int mi = 0; mi < 4; ++mi)
#pragma unroll
    for (int ni = 0; ni < 4; ++ni)
#pragma unroll
      for (int r = 0; r < 4; ++r){
        const int rr = row0 + wr*64 + mi*16 + l4*4 + r;
        const int cc = col0 + wc*64 + ni*16 + l15;
        pp[((long)z*CAPN + rr)*DD + cc] = acc[mi][ni][r];
      }
}

// fused: reduce split-K partials + bias + gate + residual add
__global__ __launch_bounds__(256) void k_combine(float* __restrict__ out,
    const int* __restrict__ slot_of, const float2* __restrict__ tok_g,
    const float* __restrict__ partial, const float* __restrict__ b2)
{
  const int tok = blockIdx.x, c = threadIdx.x * 4;
  float4 o = *(float4*)(out + (long)tok*DD + c);
  const int2 ss = *(const int2*)(slot_of + tok*2);
  const float2 g = tok_g[tok];
#pragma unroll
  for (int j = 0; j < 2; ++j){
    const int s = j ? ss.y : ss.x;
    const float gw = j ? g.y : g.x;
    if (s >= 0){
      const int e = s >> 9;
      float4 a = *(const float4*)(b2 + e*DD + c);
#pragma unroll
      for (int ks = 0; ks < 4; ++ks){
        const float4 pv = *(const float4*)(partial + (long)ks*NEXPERT*CAPN*DD + (long)s*DD + c);
        a.x += pv.x; a.y += pv.y; a.z += pv.z; a.w += pv.w;
      }
      o.x += gw*a.x; o.y += gw*a.y; o.z += gw*a.z; o.w += gw*a.w;
    }
  }
  *(float4*)(out + (long)tok*DD + c) = o;
}

// ---------------------------------------------------------------- launcher
extern "C" void kernel_launch(void* const* d_in, const int* in_sizes, int n_in,
                              void* d_out, int out_size, void* d_ws, size_t ws_size,
                              hipStream_t stream)
{
  (void)in_sizes; (void)n_in; (void)out_size; (void)ws_size;
  const float* x      = (const float*)d_in[0];
  const float* noise  = (const float*)d_in[1];
  const float* ln1_g  = (const float*)d_in[2];
  const float* ln1_b  = (const float*)d_in[3];
  const float* ln2_g  = (const float*)d_in[4];
  const float* ln2_b  = (const float*)d_in[5];
  const float* w_qkv  = (const float*)d_in[6];
  const float* w_proj = (const float*)d_in[7];
  const float* w_rl   = (const float*)d_in[8];
  const float* b_rl   = (const float*)d_in[9];
  const float* w_rn   = (const float*)d_in[10];
  const float* b_rn   = (const float*)d_in[11];
  const float* w1     = (const float*)d_in[12];
  const float* b1     = (const float*)d_in[13];
  const float* w2     = (const float*)d_in[14];
  const float* b2     = (const float*)d_in[15];
  float* out = (float*)d_out;

  char* p = (char*)d_ws;
  auto carve = [&](size_t bytes) -> void* {
    void* r = (void*)p;
    p += (bytes + 255) & ~(size_t)255;
    return r;
  };
  const size_t SLOT = (size_t)NTOK*DD*2;   // 4 MiB
  float* sin_t      = (float*)carve((size_t)TB*32*4);
  float* cos_t      = (float*)carve((size_t)TB*32*4);
  char*  region     = (char*)carve(SLOT*8);
  u16*   h1   = (u16*)region;                 // dead after qkv gemm
  u16*   qkv  = (u16*)(region + SLOT);        // slots 1-3, dead after rope
  u16*   q_r  = (u16*)(region + SLOT*4);
  u16*   k_r  = (u16*)(region + SLOT*5);
  u16*   v_t  = (u16*)(region + SLOT*6);
  u16*   ao   = (u16*)(region + SLOT*7);
  u16*   aoc  = (u16*)region;                 // slots 0-1 (8.4MB), attn chunks
  float2* mLc = (float2*)(region + SLOT*2);   // 1MB, attn chunk stats
  u16*   act  = (u16*)region;                 // full region (33.5MB), MoE phase
  u16*   h2b        = (u16*)  carve((size_t)NTOK*DD*2);
  float* h2f        = (float*)carve((size_t)NTOK*DD*4);
  int2*  tok_e      = (int2*) carve((size_t)NTOK*8);
  float2* tok_g     = (float2*)carve((size_t)NTOK*8);
  int*   slot_of    = (int*)  carve((size_t)NTOK*2*4);
  int*   expert_tok = (int*)  carve((size_t)NEXPERT*CAPN*4);
  u16*   wqkvT      = (u16*)  carve((size_t)DD*3*DD*2);
  u16*   wprojT     = (u16*)  carve((size_t)DD*DD*2);
  u16*   w1T        = (u16*)  carve((size_t)NEXPERT*DD*DFF*2);   // 67MB
  u16*   w2T        = (u16*)  carve((size_t)NEXPERT*DFF*DD*2);   // 67MB
  float* partial    = (float*)w1T;            // aliases w1T (dead after ffn1)

  k_init   <<<16, 256, 0, stream>>>(expert_tok, slot_of);
  k_sincos <<<128, 256, 0, stream>>>(sin_t, cos_t);
  k_wt     <<<dim3(48, 16, 1), 256, 0, stream>>>(w_qkv, wqkvT, DD, 3*DD);
  k_wt     <<<dim3(16, 16, 1), 256, 0, stream>>>(w_proj, wprojT, DD, DD);
  k_wt     <<<dim3(64, 16, NEXPERT), 256, 0, stream>>>(w1, w1T, DD, DFF);
  k_wt     <<<dim3(16, 64, NEXPERT), 256, 0, stream>>>(w2, w2T, DFF, DD);
  k_ln     <<<NTOK, 256, 0, stream>>>(x, ln1_g, ln1_b, h1, nullptr);
  k_gemm_qkv<<<384, 256, 0, stream>>>(h1, wqkvT, qkv);
  k_rope   <<<dim3(16, 32), 256, 0, stream>>>(qkv, sin_t, cos_t, q_r, k_r, v_t);
  k_attn   <<<dim3(8, 32, 2), 512, 0, stream>>>(q_r, k_r, v_t, aoc, mLc);
  k_attn_comb<<<256, 256, 0, stream>>>(aoc, mLc, ao);
  k_gemm_proj<<<128, 256, 0, stream>>>(ao, wprojT, x, out);
  k_ln     <<<NTOK, 256, 0, stream>>>(out, ln2_g, ln2_b, h2b, h2f);
  k_router <<<NTOK, 256, 0, stream>>>(h2f, w_rl, b_rl, w_rn, b_rn, noise, tok_e, tok_g);
  k_assign <<<NEXPERT, 256, 0, stream>>>(tok_e, expert_tok, slot_of);
  k_ffn1   <<<dim3(128, 1, NEXPERT), 256, 0, stream>>>(h2b, w1T, b1, expert_tok, act);
  k_ffn2   <<<dim3(128, 1, NEXPERT), 256, 0, stream>>>(act, w2T, partial);
  k_combine<<<NTOK, 256, 0, stream>>>(out, slot_of, tok_g, partial, b2);
}